// Round 8
// baseline (176.144 us; speedup 1.0000x reference)
//
#include <hip/hip_runtime.h>
#include <hip/hip_bf16.h>

#define NB 16384
#define DIN 512
#define H1 256
#define H2 128
#define NE 18
#define NT 3
#define NGH 64
#define NETOT 14

typedef float f32x4 __attribute__((ext_vector_type(4)));
typedef short s16x8 __attribute__((ext_vector_type(8)));
typedef unsigned short u16;
typedef unsigned int u32;

__device__ __forceinline__ u16 f2bf(float f) {
    union { float f; u32 u; } v; v.f = f;
    u32 r = v.u + 0x7fffu + ((v.u >> 16) & 1u);
    return (u16)(r >> 16);
}
__device__ __forceinline__ float bf2f(u16 u) {
    union { u32 u; float f; } v; v.u = ((u32)u) << 16;
    return v.f;
}
__device__ __forceinline__ u32 cvtpk(float a, float b) {
    u32 r;
    asm("v_cvt_pk_bf16_f32 %0, %1, %2" : "=v"(r) : "v"(a), "v"(b));
    return r;
}

#define GLDS16(g, l) __builtin_amdgcn_global_load_lds((const u32*)(g), (u32*)(l), 16, 0, 0)

// ---------------- prep: x cvt + ALL weight transposes, one launch ----------------
__global__ __launch_bounds__(256) void k_prep(
    const float* __restrict__ x, u16* __restrict__ xb,
    const float* __restrict__ sW1, const float* __restrict__ dW1, const float* __restrict__ tW1,
    const float* __restrict__ sW2, const float* __restrict__ dW2, const float* __restrict__ tW2,
    const float* __restrict__ gW1, u16* __restrict__ w1t, u16* __restrict__ w2t, u16* __restrict__ gw1t)
{
    __shared__ float lds[64 * 65];
    int bx = blockIdx.x;
    if (bx < 8192) {
        int i = (bx * 256 + threadIdx.x) * 4;
        float4 v = *reinterpret_cast<const float4*>(x + i);
        ushort4 o;
        o.x = f2bf(v.x); o.y = f2bf(v.y); o.z = f2bf(v.z); o.w = f2bf(v.w);
        *reinterpret_cast<ushort4*>(xb + i) = o;
        return;
    }
    int b = bx - 8192;
    const float* src; u16* dst; int K, N, k0, n0;
    if (b < 576) {
        int e = b >> 5, tile = b & 31;
        src = (e < 4) ? sW1 + (size_t)e * DIN * H1 : (e < 12) ? dW1 + (size_t)(e - 4) * DIN * H1
                                                              : tW1 + (size_t)(e - 12) * DIN * H1;
        dst = w1t + (size_t)e * H1 * DIN; K = DIN; N = H1;
        k0 = (tile >> 2) * 64; n0 = (tile & 3) * 64;
    } else if (b < 720) {
        int b2 = b - 576; int e = b2 >> 3, tile = b2 & 7;
        src = (e < 4) ? sW2 + (size_t)e * H1 * H2 : (e < 12) ? dW2 + (size_t)(e - 4) * H1 * H2
                                                             : tW2 + (size_t)(e - 12) * H1 * H2;
        dst = w2t + (size_t)e * H2 * H1; K = H1; N = H2;
        k0 = (tile >> 1) * 64; n0 = (tile & 1) * 64;
    } else {
        int b3 = b - 720; int t = b3 >> 3, tile = b3 & 7;
        src = gW1 + (size_t)t * DIN * NGH; dst = gw1t + (size_t)t * NGH * DIN; K = DIN; N = NGH;
        k0 = tile * 64; n0 = 0;
    }
    int t = threadIdx.x;
#pragma unroll
    for (int i = 0; i < 16; ++i) {
        int idx = i * 256 + t;
        int kk = idx >> 6, nn = idx & 63;
        lds[kk * 65 + nn] = src[(size_t)(k0 + kk) * N + n0 + nn];
    }
    __syncthreads();
#pragma unroll
    for (int i = 0; i < 16; ++i) {
        int idx = i * 256 + t;
        int nn = idx >> 6, kk = idx & 63;
        dst[(size_t)(n0 + nn) * K + k0 + kk] = f2bf(lds[kk * 65 + nn]);
    }
}

// ---------------- fused expert (+gate) kernel, 4 blocks/CU ----------------
// blocks [0,4608): experts, BM=64. 256 threads = 4 waves (wn = w), wave tile 64x64.
//   BK=32, double-buffered staging (40KB) with counted vmcnt(5); hs [64][528B] overlay.
// blocks [4608,4864): gate path (ghs in bf16 to fit 40KB).
__global__ __launch_bounds__(256, 4) void k_expert_gate(
    const u16* __restrict__ xb, const u16* __restrict__ w1t, const u16* __restrict__ w2t,
    const float* __restrict__ sb1, const float* __restrict__ db1, const float* __restrict__ tb1,
    const float* __restrict__ sb2, const float* __restrict__ db2, const float* __restrict__ tb2,
    u16* __restrict__ eout,
    const u16* __restrict__ gw1t, const float* __restrict__ gb1,
    const float* __restrict__ gw2, const float* __restrict__ gb2, float* __restrict__ gates)
{
    // expert LDS: buf c @ c*20480: xs [0,4K), w1s [4K,20K)  (40KB total dbuf)
    //             GEMM2: hs [64][528B] @ 0 (33792 B, overlays staging)
    __shared__ __align__(128) char smem[40960];

    const int bid = blockIdx.x;
    const int tid = threadIdx.x;

    if (bid >= 4608) {
        // ================= GATE PATH =================
        u16* xs  = reinterpret_cast<u16*>(smem);
        u16* g1s = reinterpret_cast<u16*>(smem) + 4608;
        u16* ghs = reinterpret_cast<u16*>(smem);          // phase2: bf16 [64][200]

        int m0 = (bid - 4608) * 64;
        int w = tid >> 6, lane = tid & 63;
        int wm = w & 1, wn = w >> 1;
        int l15 = lane & 15, lk = (lane >> 4) * 8, lr4 = (lane >> 4) * 4;

        f32x4 acc[2][6];
#pragma unroll
        for (int i = 0; i < 2; ++i)
#pragma unroll
            for (int j = 0; j < 6; ++j) acc[i][j] = (f32x4)0.f;

        const u16* xg = xb + (size_t)m0 * DIN;
        int srow = tid >> 3, su = (tid & 7) * 8;
        for (int kc = 0; kc < DIN / 64; ++kc) {
#pragma unroll
            for (int it = 0; it < 2; ++it) {
                int rr = srow + it * 32;
                *reinterpret_cast<uint4*>(&xs[rr * 72 + su]) =
                    *reinterpret_cast<const uint4*>(xg + (size_t)rr * DIN + kc * 64 + su);
            }
#pragma unroll
            for (int it = 0; it < 6; ++it) {
                int rr = srow + it * 32;
                *reinterpret_cast<uint4*>(&g1s[rr * 72 + su]) =
                    *reinterpret_cast<const uint4*>(gw1t + (size_t)rr * DIN + kc * 64 + su);
            }
            __syncthreads();
            s16x8 af[2][2], bfr[6][2];
#pragma unroll
            for (int mi = 0; mi < 2; ++mi)
#pragma unroll
                for (int kk = 0; kk < 2; ++kk)
                    af[mi][kk] = *reinterpret_cast<const s16x8*>(&xs[(wm * 32 + mi * 16 + l15) * 72 + kk * 32 + lk]);
#pragma unroll
            for (int nj = 0; nj < 6; ++nj)
#pragma unroll
                for (int kk = 0; kk < 2; ++kk)
                    bfr[nj][kk] = *reinterpret_cast<const s16x8*>(&g1s[(wn * 96 + nj * 16 + l15) * 72 + kk * 32 + lk]);
#pragma unroll
            for (int kk = 0; kk < 2; ++kk)
#pragma unroll
                for (int mi = 0; mi < 2; ++mi)
#pragma unroll
                    for (int nj = 0; nj < 6; ++nj)
                        acc[mi][nj] = __builtin_amdgcn_mfma_f32_16x16x32_bf16(af[mi][kk], bfr[nj][kk], acc[mi][nj], 0, 0, 0);
            __syncthreads();
        }
#pragma unroll
        for (int mi = 0; mi < 2; ++mi)
#pragma unroll
            for (int nj = 0; nj < 6; ++nj) {
                int col = wn * 96 + nj * 16 + l15;
                float bias = gb1[col];
#pragma unroll
                for (int r = 0; r < 4; ++r) {
                    int row = wm * 32 + mi * 16 + lr4 + r;
                    float v = acc[mi][nj][r] + bias;
                    ghs[row * 200 + col] = f2bf(v > 0.f ? v : 0.f);
                }
            }
        __syncthreads();

        if (tid < 192) {
            int tt = tid >> 6, rr = tid & 63;
            float logit[NETOT];
#pragma unroll
            for (int e2 = 0; e2 < NETOT; ++e2) logit[e2] = gb2[tt * NETOT + e2];
            const float* g2 = gw2 + tt * NGH * NETOT;
            const u16* gr = &ghs[rr * 200 + tt * 64];
            for (int g = 0; g < NGH; ++g) {
                float v = bf2f(gr[g]);
#pragma unroll
                for (int e2 = 0; e2 < NETOT; ++e2) logit[e2] += v * g2[g * NETOT + e2];
            }
            float m = logit[0];
#pragma unroll
            for (int e2 = 1; e2 < NETOT; ++e2) m = fmaxf(m, logit[e2]);
            float s = 0.f, p[NETOT];
#pragma unroll
            for (int e2 = 0; e2 < NETOT; ++e2) { p[e2] = __expf(logit[e2] - m); s += p[e2]; }
            float inv = 1.f / s;
            float* go = gates + (size_t)(m0 + rr) * (NT * NETOT) + tt * NETOT;
#pragma unroll
            for (int e2 = 0; e2 < NETOT; ++e2) go[e2] = p[e2] * inv;
        }
        return;
    }

    // ================= EXPERT PATH (BM=64) =================
    const int e  = bid >> 8;
    const int m0 = (bid & 255) * 64;
    const int w = tid >> 6, lane = tid & 63;     // 4 waves; w = N-quarter
    const int l15 = lane & 15, q = lane >> 4;
    const int q16 = q * 16;
    const int swk = ((l15 >> 1) & 3) << 4;       // BK=32 row (64B) swizzle

    const u16* xg  = xb + (size_t)m0 * DIN;
    const u16* w1g = w1t + (size_t)e * H1 * DIN;
    const u16* w2g = w2t + (size_t)e * H2 * H1;
    const float* b1p = (e < 4) ? sb1 + e * H1 : (e < 12) ? db1 + (e - 4) * H1 : tb1 + (e - 12) * H1;
    const float* b2p = (e < 4) ? sb2 + e * H2 : (e < 12) ? db2 + (e - 4) * H2 : tb2 + (e - 12) * H2;

    // staging: per-lane inverse-swizzled global src, wave-uniform LDS dest
    const int sr = lane >> 2, sc = lane & 3;
    const int xrow = w * 16 + sr;
    const u16* gx = xg + (size_t)xrow * DIN + ((sc ^ ((xrow >> 1) & 3)) * 8);
    const int lx = w * 1024;                     // + buf*20480
    const u16* gw1[4]; int lw1[4];
#pragma unroll
    for (int j = 0; j < 4; ++j) {
        int row = w * 64 + j * 16 + sr;
        gw1[j] = w1g + (size_t)row * DIN + ((sc ^ ((row >> 1) & 3)) * 8);
        lw1[j] = 4096 + w * 4096 + j * 1024;     // + buf*20480
    }

    // fragment offsets within current buf
    int offX[4], offW[4];
#pragma unroll
    for (int mi = 0; mi < 4; ++mi)
        offX[mi] = (mi * 16 + l15) * 64 + (q16 ^ swk);
#pragma unroll
    for (int nj = 0; nj < 4; ++nj)
        offW[nj] = 4096 + (w * 64 + nj * 16 + l15) * 64 + (q16 ^ swk);

    f32x4 acc1[4][4];
#pragma unroll
    for (int i = 0; i < 4; ++i)
#pragma unroll
        for (int j = 0; j < 4; ++j) acc1[i][j] = (f32x4)0.f;

    // ---- GEMM1: h[64,256] = x[64,512] @ W1t^T, 16 K-tiles BK=32, counted-wait dbuf ----
    GLDS16(gx, smem + lx);
#pragma unroll
    for (int j = 0; j < 4; ++j) GLDS16(gw1[j], smem + lw1[j]);

    for (int kt = 0; kt < 16; ++kt) {
        if (kt < 15) {
            const int nb = ((kt + 1) & 1) * 20480, ko = (kt + 1) * 32;
            GLDS16(gx + ko, smem + nb + lx);
#pragma unroll
            for (int j = 0; j < 4; ++j) GLDS16(gw1[j] + ko, smem + nb + lw1[j]);
            asm volatile("s_waitcnt vmcnt(5)" ::: "memory");   // tile-kt's 5 loads done
        } else {
            asm volatile("s_waitcnt vmcnt(0)" ::: "memory");
        }
        __builtin_amdgcn_s_barrier();

        const char* cb = smem + (kt & 1) * 20480;
        s16x8 xf[4], wf[4];
#pragma unroll
        for (int nj = 0; nj < 4; ++nj) wf[nj] = *(const s16x8*)(cb + offW[nj]);
#pragma unroll
        for (int mi = 0; mi < 4; ++mi) xf[mi] = *(const s16x8*)(cb + offX[mi]);
        __builtin_amdgcn_s_setprio(1);
#pragma unroll
        for (int mi = 0; mi < 4; ++mi)
#pragma unroll
            for (int nj = 0; nj < 4; ++nj)   // SWAPPED: A=W1, B=x -> C col = m (l15), row = n (q*4+r)
                acc1[mi][nj] = __builtin_amdgcn_mfma_f32_16x16x32_bf16(wf[nj], xf[mi], acc1[mi][nj], 0, 0, 0);
        __builtin_amdgcn_s_setprio(0);
        asm volatile("s_waitcnt lgkmcnt(0)" ::: "memory");
        __builtin_amdgcn_s_barrier();
    }

    // ---- h = relu(acc1 + b1) -> hs [64 rows][528 B] ----
#pragma unroll
    for (int mi = 0; mi < 4; ++mi) {
        const int m = mi * 16 + l15;
        char* rowp = smem + m * 528;
#pragma unroll
        for (int nj = 0; nj < 4; ++nj) {
            const int n0 = w * 64 + nj * 16 + q * 4;
            const float4 bv = *reinterpret_cast<const float4*>(b1p + n0);
            float v0 = fmaxf(acc1[mi][nj][0] + bv.x, 0.f);
            float v1 = fmaxf(acc1[mi][nj][1] + bv.y, 0.f);
            float v2 = fmaxf(acc1[mi][nj][2] + bv.z, 0.f);
            float v3 = fmaxf(acc1[mi][nj][3] + bv.w, 0.f);
            uint2 hv; hv.x = cvtpk(v0, v1); hv.y = cvtpk(v2, v3);
            *reinterpret_cast<uint2*>(rowp + n0 * 2) = hv;
        }
    }
    __syncthreads();

    // ---- GEMM2: o[64,128] = h[64,256] @ W2t^T; W2 from global; no barriers ----
    f32x4 acc2[4][2];
#pragma unroll
    for (int i = 0; i < 4; ++i)
#pragma unroll
        for (int j = 0; j < 2; ++j) acc2[i][j] = (f32x4)0.f;
    const u16* w2p0 = w2g + (size_t)(w * 32 + l15) * H1 + q * 8;
    const u16* w2p1 = w2g + (size_t)(w * 32 + 16 + l15) * H1 + q * 8;
#pragma unroll
    for (int kt2 = 0; kt2 < 8; ++kt2) {
        s16x8 wf2[2], hf[4];
        wf2[0] = *(const s16x8*)(w2p0 + kt2 * 32);
        wf2[1] = *(const s16x8*)(w2p1 + kt2 * 32);
#pragma unroll
        for (int mi = 0; mi < 4; ++mi)
            hf[mi] = *(const s16x8*)(smem + (mi * 16 + l15) * 528 + kt2 * 64 + q16);
#pragma unroll
        for (int mi = 0; mi < 4; ++mi)
#pragma unroll
            for (int pj = 0; pj < 2; ++pj)
                acc2[mi][pj] = __builtin_amdgcn_mfma_f32_16x16x32_bf16(hf[mi], wf2[pj], acc2[mi][pj], 0, 0, 0);
    }

    // ---- epilogue: relu(acc2 + b2) -> eout[e][b][h] bf16 ----
    u16* eo = eout + ((size_t)e * NB + m0) * H2;
#pragma unroll
    for (int mi = 0; mi < 4; ++mi)
#pragma unroll
        for (int pj = 0; pj < 2; ++pj) {
            const int p = w * 32 + pj * 16 + l15;
            const float bias = b2p[p];
#pragma unroll
            for (int r = 0; r < 4; ++r) {
                const int row = mi * 16 + q * 4 + r;
                float v = acc2[mi][pj][r] + bias;
                eo[(size_t)row * H2 + p] = f2bf(v > 0.f ? v : 0.f);
            }
        }
}

// ---------------- combine ----------------
__global__ __launch_bounds__(256) void k_combine(
    const u16* __restrict__ eout, const float* __restrict__ gates, float* __restrict__ out)
{
    int tid = threadIdx.x;
    int lr = tid >> 5, hq = tid & 31;
    int b = blockIdx.x * 8 + lr;
    int h0 = hq * 4;
    const float* g = gates + (size_t)b * (NT * NETOT);
    float o0[4] = {0, 0, 0, 0}, o1[4] = {0, 0, 0, 0}, o2[4] = {0, 0, 0, 0};
#pragma unroll
    for (int e = 0; e < NE; ++e) {
        ushort4 ev = *reinterpret_cast<const ushort4*>(&eout[((size_t)e * NB + b) * H2 + h0]);
        float v0 = bf2f(ev.x), v1 = bf2f(ev.y), v2 = bf2f(ev.z), v3 = bf2f(ev.w);
        if (e < 12) {
            float wa = g[e], wb = g[NETOT + e], wc = g[2 * NETOT + e];
            o0[0] += wa * v0; o0[1] += wa * v1; o0[2] += wa * v2; o0[3] += wa * v3;
            o1[0] += wb * v0; o1[1] += wb * v1; o1[2] += wb * v2; o1[3] += wb * v3;
            o2[0] += wc * v0; o2[1] += wc * v1; o2[2] += wc * v2; o2[3] += wc * v3;
        } else {
            int t = (e - 12) >> 1, te = (e - 12) & 1;
            float wt = g[t * NETOT + 12 + te];
            float* ot = (t == 0) ? o0 : (t == 1) ? o1 : o2;
            ot[0] += wt * v0; ot[1] += wt * v1; ot[2] += wt * v2; ot[3] += wt * v3;
        }
    }
    size_t base = (size_t)b * H2 + h0;
    *reinterpret_cast<float4*>(&out[0 * (size_t)NB * H2 + base]) = make_float4(o0[0], o0[1], o0[2], o0[3]);
    *reinterpret_cast<float4*>(&out[1 * (size_t)NB * H2 + base]) = make_float4(o1[0], o1[1], o1[2], o1[3]);
    *reinterpret_cast<float4*>(&out[2 * (size_t)NB * H2 + base]) = make_float4(o2[0], o2[1], o2[2], o2[3]);
}

extern "C" void kernel_launch(void* const* d_in, const int* in_sizes, int n_in,
                              void* d_out, int out_size, void* d_ws, size_t ws_size,
                              hipStream_t stream)
{
    const float* x   = (const float*)d_in[0];
    const float* sW1 = (const float*)d_in[2];
    const float* sb1 = (const float*)d_in[3];
    const float* sW2 = (const float*)d_in[4];
    const float* sb2 = (const float*)d_in[5];
    const float* dW1 = (const float*)d_in[6];
    const float* db1 = (const float*)d_in[7];
    const float* dW2 = (const float*)d_in[8];
    const float* db2 = (const float*)d_in[9];
    const float* tW1 = (const float*)d_in[10];
    const float* tb1 = (const float*)d_in[11];
    const float* tW2 = (const float*)d_in[12];
    const float* tb2 = (const float*)d_in[13];
    const float* gW1 = (const float*)d_in[14];
    const float* gb1 = (const float*)d_in[15];
    const float* gW2 = (const float*)d_in[16];
    const float* gb2 = (const float*)d_in[17];

    char* ws = (char*)d_ws;
    u16*  xb    = (u16*)(ws + 0);
    u16*  w1t   = (u16*)(ws + 16777216);
    u16*  w2t   = (u16*)(ws + 21495808);
    u16*  gw1t  = (u16*)(ws + 22675456);
    float* gates = (float*)(ws + 22872064);
    u16*  eout  = (u16*)(ws + 25624576);

    k_prep<<<dim3(8936), dim3(256), 0, stream>>>(x, xb, sW1, dW1, tW1, sW2, dW2, tW2, gW1, w1t, w2t, gw1t);
    k_expert_gate<<<dim3(4864), dim3(256), 0, stream>>>(xb, w1t, w2t, sb1, db1, tb1, sb2, db2, tb2,
                                                        eout, gw1t, gb1, gW2, gb2, gates);
    k_combine<<<dim3(NB / 8), dim3(256), 0, stream>>>(eout, gates, (float*)d_out);
}

// Round 9
// 148.721 us; speedup vs baseline: 1.1844x; 1.1844x over previous
//
#include <hip/hip_runtime.h>
#include <hip/hip_bf16.h>

#define NB 16384
#define DIN 512
#define H1 256
#define H2 128
#define NE 18
#define NT 3
#define NGH 64
#define NETOT 14

typedef float f32x4 __attribute__((ext_vector_type(4)));
typedef short s16x8 __attribute__((ext_vector_type(8)));
typedef unsigned short u16;
typedef unsigned int u32;

__device__ __forceinline__ u16 f2bf(float f) {
    union { float f; u32 u; } v; v.f = f;
    u32 r = v.u + 0x7fffu + ((v.u >> 16) & 1u);
    return (u16)(r >> 16);
}
__device__ __forceinline__ float bf2f(u16 u) {
    union { u32 u; float f; } v; v.u = ((u32)u) << 16;
    return v.f;
}
__device__ __forceinline__ u32 cvtpk(float a, float b) {
    u32 r;
    asm("v_cvt_pk_bf16_f32 %0, %1, %2" : "=v"(r) : "v"(a), "v"(b));
    return r;
}

#define GLDS16(g, l) __builtin_amdgcn_global_load_lds((const u32*)(g), (u32*)(l), 16, 0, 0)

// ---------------- prep: x cvt + ALL weight transposes, one launch ----------------
__global__ __launch_bounds__(256) void k_prep(
    const float* __restrict__ x, u16* __restrict__ xb,
    const float* __restrict__ sW1, const float* __restrict__ dW1, const float* __restrict__ tW1,
    const float* __restrict__ sW2, const float* __restrict__ dW2, const float* __restrict__ tW2,
    const float* __restrict__ gW1, u16* __restrict__ w1t, u16* __restrict__ w2t, u16* __restrict__ gw1t)
{
    __shared__ float lds[64 * 65];
    int bx = blockIdx.x;
    if (bx < 8192) {
        int i = (bx * 256 + threadIdx.x) * 4;
        float4 v = *reinterpret_cast<const float4*>(x + i);
        ushort4 o;
        o.x = f2bf(v.x); o.y = f2bf(v.y); o.z = f2bf(v.z); o.w = f2bf(v.w);
        *reinterpret_cast<ushort4*>(xb + i) = o;
        return;
    }
    int b = bx - 8192;
    const float* src; u16* dst; int K, N, k0, n0;
    if (b < 576) {
        int e = b >> 5, tile = b & 31;
        src = (e < 4) ? sW1 + (size_t)e * DIN * H1 : (e < 12) ? dW1 + (size_t)(e - 4) * DIN * H1
                                                              : tW1 + (size_t)(e - 12) * DIN * H1;
        dst = w1t + (size_t)e * H1 * DIN; K = DIN; N = H1;
        k0 = (tile >> 2) * 64; n0 = (tile & 3) * 64;
    } else if (b < 720) {
        int b2 = b - 576; int e = b2 >> 3, tile = b2 & 7;
        src = (e < 4) ? sW2 + (size_t)e * H1 * H2 : (e < 12) ? dW2 + (size_t)(e - 4) * H1 * H2
                                                             : tW2 + (size_t)(e - 12) * H1 * H2;
        dst = w2t + (size_t)e * H2 * H1; K = H1; N = H2;
        k0 = (tile >> 1) * 64; n0 = (tile & 1) * 64;
    } else {
        int b3 = b - 720; int t = b3 >> 3, tile = b3 & 7;
        src = gW1 + (size_t)t * DIN * NGH; dst = gw1t + (size_t)t * NGH * DIN; K = DIN; N = NGH;
        k0 = tile * 64; n0 = 0;
    }
    int t = threadIdx.x;
#pragma unroll
    for (int i = 0; i < 16; ++i) {
        int idx = i * 256 + t;
        int kk = idx >> 6, nn = idx & 63;
        lds[kk * 65 + nn] = src[(size_t)(k0 + kk) * N + n0 + nn];
    }
    __syncthreads();
#pragma unroll
    for (int i = 0; i < 16; ++i) {
        int idx = i * 256 + t;
        int nn = idx >> 6, kk = idx & 63;
        dst[(size_t)(n0 + nn) * K + k0 + kk] = f2bf(lds[kk * 65 + nn]);
    }
}

// ---------------- fused expert (+gate) kernel ----------------
// blocks [0,2304): experts. 256 threads = 4 waves (1M x 4N), wave tile 128x64.
//   BM=128, BN=256, BK=32, TRIPLE-buffered staging, prefetch depth 2, counted vmcnt(12).
//   GEMM2: h from padded LDS, W2 from global, no barriers.
// blocks [2304,2560): gate path.
__global__ __launch_bounds__(256, 2) void k_expert_gate(
    const u16* __restrict__ xb, const u16* __restrict__ w1t, const u16* __restrict__ w2t,
    const float* __restrict__ sb1, const float* __restrict__ db1, const float* __restrict__ tb1,
    const float* __restrict__ sb2, const float* __restrict__ db2, const float* __restrict__ tb2,
    u16* __restrict__ eout,
    const u16* __restrict__ gw1t, const float* __restrict__ gb1,
    const float* __restrict__ gw2, const float* __restrict__ gb2, float* __restrict__ gates)
{
    // expert LDS: staging buf c @ c*24576: xs [0,8K), w1s [8K,24K)  (3 bufs, 72KB)
    //             GEMM2: hs [128][528B] @ 0 (67584 B, overlays staging)
    __shared__ __align__(128) char smem[73728];

    const int bid = blockIdx.x;
    const int tid = threadIdx.x;

    if (bid >= 2304) {
        // ================= GATE PATH =================
        u16* xs  = reinterpret_cast<u16*>(smem);
        u16* g1s = reinterpret_cast<u16*>(smem) + 4608;
        float* ghs = reinterpret_cast<float*>(smem);

        int m0 = (bid - 2304) * 64;
        int w = tid >> 6, lane = tid & 63;
        int wm = w & 1, wn = w >> 1;
        int l15 = lane & 15, lk = (lane >> 4) * 8, lr4 = (lane >> 4) * 4;

        f32x4 acc[2][6];
#pragma unroll
        for (int i = 0; i < 2; ++i)
#pragma unroll
            for (int j = 0; j < 6; ++j) acc[i][j] = (f32x4)0.f;

        const u16* xg = xb + (size_t)m0 * DIN;
        int srow = tid >> 3, su = (tid & 7) * 8;
        for (int kc = 0; kc < DIN / 64; ++kc) {
#pragma unroll
            for (int it = 0; it < 2; ++it) {
                int rr = srow + it * 32;
                *reinterpret_cast<uint4*>(&xs[rr * 72 + su]) =
                    *reinterpret_cast<const uint4*>(xg + (size_t)rr * DIN + kc * 64 + su);
            }
#pragma unroll
            for (int it = 0; it < 6; ++it) {
                int rr = srow + it * 32;
                *reinterpret_cast<uint4*>(&g1s[rr * 72 + su]) =
                    *reinterpret_cast<const uint4*>(gw1t + (size_t)rr * DIN + kc * 64 + su);
            }
            __syncthreads();
            s16x8 af[2][2], bfr[6][2];
#pragma unroll
            for (int mi = 0; mi < 2; ++mi)
#pragma unroll
                for (int kk = 0; kk < 2; ++kk)
                    af[mi][kk] = *reinterpret_cast<const s16x8*>(&xs[(wm * 32 + mi * 16 + l15) * 72 + kk * 32 + lk]);
#pragma unroll
            for (int nj = 0; nj < 6; ++nj)
#pragma unroll
                for (int kk = 0; kk < 2; ++kk)
                    bfr[nj][kk] = *reinterpret_cast<const s16x8*>(&g1s[(wn * 96 + nj * 16 + l15) * 72 + kk * 32 + lk]);
#pragma unroll
            for (int kk = 0; kk < 2; ++kk)
#pragma unroll
                for (int mi = 0; mi < 2; ++mi)
#pragma unroll
                    for (int nj = 0; nj < 6; ++nj)
                        acc[mi][nj] = __builtin_amdgcn_mfma_f32_16x16x32_bf16(af[mi][kk], bfr[nj][kk], acc[mi][nj], 0, 0, 0);
            __syncthreads();
        }
#pragma unroll
        for (int mi = 0; mi < 2; ++mi)
#pragma unroll
            for (int nj = 0; nj < 6; ++nj) {
                int col = wn * 96 + nj * 16 + l15;
                float bias = gb1[col];
#pragma unroll
                for (int r = 0; r < 4; ++r) {
                    int row = wm * 32 + mi * 16 + lr4 + r;
                    float v = acc[mi][nj][r] + bias;
                    ghs[row * 200 + col] = v > 0.f ? v : 0.f;
                }
            }
        __syncthreads();

        if (tid < 192) {
            int tt = tid >> 6, rr = tid & 63;
            float logit[NETOT];
#pragma unroll
            for (int e2 = 0; e2 < NETOT; ++e2) logit[e2] = gb2[tt * NETOT + e2];
            const float* g2 = gw2 + tt * NGH * NETOT;
            const float* gr = &ghs[rr * 200 + tt * 64];
            for (int g = 0; g < NGH; ++g) {
                float v = gr[g];
#pragma unroll
                for (int e2 = 0; e2 < NETOT; ++e2) logit[e2] += v * g2[g * NETOT + e2];
            }
            float m = logit[0];
#pragma unroll
            for (int e2 = 1; e2 < NETOT; ++e2) m = fmaxf(m, logit[e2]);
            float s = 0.f, p[NETOT];
#pragma unroll
            for (int e2 = 0; e2 < NETOT; ++e2) { p[e2] = __expf(logit[e2] - m); s += p[e2]; }
            float inv = 1.f / s;
            float* go = gates + (size_t)(m0 + rr) * (NT * NETOT) + tt * NETOT;
#pragma unroll
            for (int e2 = 0; e2 < NETOT; ++e2) go[e2] = p[e2] * inv;
        }
        return;
    }

    // ================= EXPERT PATH =================
    const int e  = bid >> 7;
    const int m0 = (bid & 127) * 128;
    const int w = tid >> 6, lane = tid & 63;     // 4 waves, wn = w
    const int l15 = lane & 15, q = lane >> 4;
    const int q16 = q * 16;
    const int swk = ((l15 >> 1) & 3) << 4;       // BK=32 row (64B) swizzle

    const u16* xg  = xb + (size_t)m0 * DIN;
    const u16* w1g = w1t + (size_t)e * H1 * DIN;
    const u16* w2g = w2t + (size_t)e * H2 * H1;
    const float* b1p = (e < 4) ? sb1 + e * H1 : (e < 12) ? db1 + (e - 4) * H1 : tb1 + (e - 12) * H1;
    const float* b2p = (e < 4) ? sb2 + e * H2 : (e < 12) ? db2 + (e - 4) * H2 : tb2 + (e - 12) * H2;

    // staging: per-lane inverse-swizzled global src, wave-uniform LDS dest
    const int sr = lane >> 2, sc = lane & 3;
    const u16* gx[2]; int lx[2];
#pragma unroll
    for (int j = 0; j < 2; ++j) {
        int row = w * 32 + j * 16 + sr;
        gx[j] = xg + (size_t)row * DIN + ((sc ^ ((row >> 1) & 3)) * 8);
        lx[j] = w * 2048 + j * 1024;           // + buf*24576
    }
    const u16* gw1[4]; int lw1[4];
#pragma unroll
    for (int j = 0; j < 4; ++j) {
        int row = w * 64 + j * 16 + sr;
        gw1[j] = w1g + (size_t)row * DIN + ((sc ^ ((row >> 1) & 3)) * 8);
        lw1[j] = 8192 + w * 4096 + j * 1024;   // + buf*24576
    }

    // fragment offsets within current buf
    int offX[8], offW[4];
#pragma unroll
    for (int mi = 0; mi < 8; ++mi)
        offX[mi] = (mi * 16 + l15) * 64 + (q16 ^ swk);
#pragma unroll
    for (int nj = 0; nj < 4; ++nj)
        offW[nj] = 8192 + (w * 64 + nj * 16 + l15) * 64 + (q16 ^ swk);

    f32x4 acc1[8][4];
#pragma unroll
    for (int i = 0; i < 8; ++i)
#pragma unroll
        for (int j = 0; j < 4; ++j) acc1[i][j] = (f32x4)0.f;

    // ---- GEMM1: h[128,256] = x[128,512] @ W1t^T, 16 K-tiles BK=32 ----
    // TRIPLE-buffered, prefetch depth 2, counted vmcnt(12).
    // prologue: kt=0 -> buf0, kt=1 -> buf1
#pragma unroll
    for (int j = 0; j < 2; ++j) GLDS16(gx[j], smem + lx[j]);
#pragma unroll
    for (int j = 0; j < 4; ++j) GLDS16(gw1[j], smem + lw1[j]);
#pragma unroll
    for (int j = 0; j < 2; ++j) GLDS16(gx[j] + 32, smem + 24576 + lx[j]);
#pragma unroll
    for (int j = 0; j < 4; ++j) GLDS16(gw1[j] + 32, smem + 24576 + lw1[j]);

    int cur = 0, stg = 2;   // buffer indices (x24576)
    for (int kt = 0; kt < 16; ++kt) {
        if (kt < 14) {
            const int sb = stg * 24576, ko = (kt + 2) * 32;
#pragma unroll
            for (int j = 0; j < 2; ++j) GLDS16(gx[j] + ko, smem + sb + lx[j]);
#pragma unroll
            for (int j = 0; j < 4; ++j) GLDS16(gw1[j] + ko, smem + sb + lw1[j]);
            asm volatile("s_waitcnt vmcnt(12)" ::: "memory");  // kt's 6 loads done; 12 newer in flight
        } else if (kt == 14) {
            asm volatile("s_waitcnt vmcnt(6)" ::: "memory");
        } else {
            asm volatile("s_waitcnt vmcnt(0)" ::: "memory");
        }
        __builtin_amdgcn_s_barrier();                           // tile-kt data visible to all

        const char* cb = smem + cur * 24576;
        s16x8 xf[8], wf[4];
#pragma unroll
        for (int nj = 0; nj < 4; ++nj) wf[nj] = *(const s16x8*)(cb + offW[nj]);
#pragma unroll
        for (int mi = 0; mi < 8; ++mi) xf[mi] = *(const s16x8*)(cb + offX[mi]);
        __builtin_amdgcn_s_setprio(1);
#pragma unroll
        for (int mi = 0; mi < 8; ++mi)
#pragma unroll
            for (int nj = 0; nj < 4; ++nj)   // SWAPPED: A=W1, B=x -> C col = m (l15), row = n (q*4+r)
                acc1[mi][nj] = __builtin_amdgcn_mfma_f32_16x16x32_bf16(wf[nj], xf[mi], acc1[mi][nj], 0, 0, 0);
        __builtin_amdgcn_s_setprio(0);
        asm volatile("s_waitcnt lgkmcnt(0)" ::: "memory");      // our ds_reads done
        __builtin_amdgcn_s_barrier();                           // buf cur free for re-stage

        cur = (cur == 2) ? 0 : cur + 1;
        stg = (stg == 2) ? 0 : stg + 1;
    }

    // ---- h = relu(acc1 + b1) -> hs [128 rows][528 B] (padded rows) ----
#pragma unroll
    for (int mi = 0; mi < 8; ++mi) {
        const int m = mi * 16 + l15;
        char* rowp = smem + m * 528;
#pragma unroll
        for (int nj = 0; nj < 4; ++nj) {
            const int n0 = w * 64 + nj * 16 + q * 4;
            const float4 bv = *reinterpret_cast<const float4*>(b1p + n0);
            float v0 = fmaxf(acc1[mi][nj][0] + bv.x, 0.f);
            float v1 = fmaxf(acc1[mi][nj][1] + bv.y, 0.f);
            float v2 = fmaxf(acc1[mi][nj][2] + bv.z, 0.f);
            float v3 = fmaxf(acc1[mi][nj][3] + bv.w, 0.f);
            uint2 hv; hv.x = cvtpk(v0, v1); hv.y = cvtpk(v2, v3);
            *reinterpret_cast<uint2*>(rowp + n0 * 2) = hv;
        }
    }
    __syncthreads();

    // ---- GEMM2: o[128,128] = h[128,256] @ W2t^T; W2 from global; no barriers ----
    f32x4 acc2[8][2];
#pragma unroll
    for (int i = 0; i < 8; ++i)
#pragma unroll
        for (int j = 0; j < 2; ++j) acc2[i][j] = (f32x4)0.f;
    const u16* w2p0 = w2g + (size_t)(w * 32 + l15) * H1 + q * 8;
    const u16* w2p1 = w2g + (size_t)(w * 32 + 16 + l15) * H1 + q * 8;
#pragma unroll
    for (int kt2 = 0; kt2 < 8; ++kt2) {
        s16x8 wf2[2], hf[8];
        wf2[0] = *(const s16x8*)(w2p0 + kt2 * 32);
        wf2[1] = *(const s16x8*)(w2p1 + kt2 * 32);
#pragma unroll
        for (int mi = 0; mi < 8; ++mi)
            hf[mi] = *(const s16x8*)(smem + (mi * 16 + l15) * 528 + kt2 * 64 + q16);
#pragma unroll
        for (int mi = 0; mi < 8; ++mi)
#pragma unroll
            for (int pj = 0; pj < 2; ++pj)
                acc2[mi][pj] = __builtin_amdgcn_mfma_f32_16x16x32_bf16(hf[mi], wf2[pj], acc2[mi][pj], 0, 0, 0);
    }

    // ---- epilogue: relu(acc2 + b2) -> eout[e][b][h] bf16 ----
    u16* eo = eout + ((size_t)e * NB + m0) * H2;
#pragma unroll
    for (int mi = 0; mi < 8; ++mi)
#pragma unroll
        for (int pj = 0; pj < 2; ++pj) {
            const int p = w * 32 + pj * 16 + l15;
            const float bias = b2p[p];
#pragma unroll
            for (int r = 0; r < 4; ++r) {
                const int row = mi * 16 + q * 4 + r;
                float v = acc2[mi][pj][r] + bias;
                eo[(size_t)row * H2 + p] = f2bf(v > 0.f ? v : 0.f);
            }
        }
}

// ---------------- combine ----------------
__global__ __launch_bounds__(256) void k_combine(
    const u16* __restrict__ eout, const float* __restrict__ gates, float* __restrict__ out)
{
    int tid = threadIdx.x;
    int lr = tid >> 5, hq = tid & 31;
    int b = blockIdx.x * 8 + lr;
    int h0 = hq * 4;
    const float* g = gates + (size_t)b * (NT * NETOT);
    float o0[4] = {0, 0, 0, 0}, o1[4] = {0, 0, 0, 0}, o2[4] = {0, 0, 0, 0};
#pragma unroll
    for (int e = 0; e < NE; ++e) {
        ushort4 ev = *reinterpret_cast<const ushort4*>(&eout[((size_t)e * NB + b) * H2 + h0]);
        float v0 = bf2f(ev.x), v1 = bf2f(ev.y), v2 = bf2f(ev.z), v3 = bf2f(ev.w);
        if (e < 12) {
            float wa = g[e], wb = g[NETOT + e], wc = g[2 * NETOT + e];
            o0[0] += wa * v0; o0[1] += wa * v1; o0[2] += wa * v2; o0[3] += wa * v3;
            o1[0] += wb * v0; o1[1] += wb * v1; o1[2] += wb * v2; o1[3] += wb * v3;
            o2[0] += wc * v0; o2[1] += wc * v1; o2[2] += wc * v2; o2[3] += wc * v3;
        } else {
            int t = (e - 12) >> 1, te = (e - 12) & 1;
            float wt = g[t * NETOT + 12 + te];
            float* ot = (t == 0) ? o0 : (t == 1) ? o1 : o2;
            ot[0] += wt * v0; ot[1] += wt * v1; ot[2] += wt * v2; ot[3] += wt * v3;
        }
    }
    size_t base = (size_t)b * H2 + h0;
    *reinterpret_cast<float4*>(&out[0 * (size_t)NB * H2 + base]) = make_float4(o0[0], o0[1], o0[2], o0[3]);
    *reinterpret_cast<float4*>(&out[1 * (size_t)NB * H2 + base]) = make_float4(o1[0], o1[1], o1[2], o1[3]);
    *reinterpret_cast<float4*>(&out[2 * (size_t)NB * H2 + base]) = make_float4(o2[0], o2[1], o2[2], o2[3]);
}

extern "C" void kernel_launch(void* const* d_in, const int* in_sizes, int n_in,
                              void* d_out, int out_size, void* d_ws, size_t ws_size,
                              hipStream_t stream)
{
    const float* x   = (const float*)d_in[0];
    const float* sW1 = (const float*)d_in[2];
    const float* sb1 = (const float*)d_in[3];
    const float* sW2 = (const float*)d_in[4];
    const float* sb2 = (const float*)d_in[5];
    const float* dW1 = (const float*)d_in[6];
    const float* db1 = (const float*)d_in[7];
    const float* dW2 = (const float*)d_in[8];
    const float* db2 = (const float*)d_in[9];
    const float* tW1 = (const float*)d_in[10];
    const float* tb1 = (const float*)d_in[11];
    const float* tW2 = (const float*)d_in[12];
    const float* tb2 = (const float*)d_in[13];
    const float* gW1 = (const float*)d_in[14];
    const float* gb1 = (const float*)d_in[15];
    const float* gW2 = (const float*)d_in[16];
    const float* gb2 = (const float*)d_in[17];

    char* ws = (char*)d_ws;
    u16*  xb    = (u16*)(ws + 0);
    u16*  w1t   = (u16*)(ws + 16777216);
    u16*  w2t   = (u16*)(ws + 21495808);
    u16*  gw1t  = (u16*)(ws + 22675456);
    float* gates = (float*)(ws + 22872064);
    u16*  eout  = (u16*)(ws + 25624576);

    k_prep<<<dim3(8936), dim3(256), 0, stream>>>(x, xb, sW1, dW1, tW1, sW2, dW2, tW2, gW1, w1t, w2t, gw1t);
    k_expert_gate<<<dim3(2560), dim3(256), 0, stream>>>(xb, w1t, w2t, sb1, db1, tb1, sb2, db2, tb2,
                                                        eout, gw1t, gb1, gW2, gb2, gates);
    k_combine<<<dim3(NB / 8), dim3(256), 0, stream>>>(eout, gates, (float*)d_out);
}

// Round 10
// 147.900 us; speedup vs baseline: 1.1910x; 1.0055x over previous
//
#include <hip/hip_runtime.h>
#include <hip/hip_bf16.h>

#define NB 16384
#define DIN 512
#define H1 256
#define H2 128
#define NE 18
#define NT 3
#define NGH 64
#define NETOT 14

typedef float f32x4 __attribute__((ext_vector_type(4)));
typedef short s16x8 __attribute__((ext_vector_type(8)));
typedef unsigned short u16;
typedef unsigned int u32;

__device__ __forceinline__ u16 f2bf(float f) {
    union { float f; u32 u; } v; v.f = f;
    u32 r = v.u + 0x7fffu + ((v.u >> 16) & 1u);
    return (u16)(r >> 16);
}
__device__ __forceinline__ float bf2f(u16 u) {
    union { u32 u; float f; } v; v.u = ((u32)u) << 16;
    return v.f;
}
__device__ __forceinline__ u32 cvtpk(float a, float b) {
    u32 r;
    asm("v_cvt_pk_bf16_f32 %0, %1, %2" : "=v"(r) : "v"(a), "v"(b));
    return r;
}

#define GLDS16(g, l) __builtin_amdgcn_global_load_lds((const u32*)(g), (u32*)(l), 16, 0, 0)

// ---------------- prep: x cvt + ALL weight transposes, one launch ----------------
__global__ __launch_bounds__(256) void k_prep(
    const float* __restrict__ x, u16* __restrict__ xb,
    const float* __restrict__ sW1, const float* __restrict__ dW1, const float* __restrict__ tW1,
    const float* __restrict__ sW2, const float* __restrict__ dW2, const float* __restrict__ tW2,
    const float* __restrict__ gW1, u16* __restrict__ w1t, u16* __restrict__ w2t, u16* __restrict__ gw1t)
{
    __shared__ float lds[64 * 65];
    int bx = blockIdx.x;
    if (bx < 8192) {
        int i = (bx * 256 + threadIdx.x) * 4;
        float4 v = *reinterpret_cast<const float4*>(x + i);
        ushort4 o;
        o.x = f2bf(v.x); o.y = f2bf(v.y); o.z = f2bf(v.z); o.w = f2bf(v.w);
        *reinterpret_cast<ushort4*>(xb + i) = o;
        return;
    }
    int b = bx - 8192;
    const float* src; u16* dst; int K, N, k0, n0;
    if (b < 576) {
        int e = b >> 5, tile = b & 31;
        src = (e < 4) ? sW1 + (size_t)e * DIN * H1 : (e < 12) ? dW1 + (size_t)(e - 4) * DIN * H1
                                                              : tW1 + (size_t)(e - 12) * DIN * H1;
        dst = w1t + (size_t)e * H1 * DIN; K = DIN; N = H1;
        k0 = (tile >> 2) * 64; n0 = (tile & 3) * 64;
    } else if (b < 720) {
        int b2 = b - 576; int e = b2 >> 3, tile = b2 & 7;
        src = (e < 4) ? sW2 + (size_t)e * H1 * H2 : (e < 12) ? dW2 + (size_t)(e - 4) * H1 * H2
                                                             : tW2 + (size_t)(e - 12) * H1 * H2;
        dst = w2t + (size_t)e * H2 * H1; K = H1; N = H2;
        k0 = (tile >> 1) * 64; n0 = (tile & 1) * 64;
    } else {
        int b3 = b - 720; int t = b3 >> 3, tile = b3 & 7;
        src = gW1 + (size_t)t * DIN * NGH; dst = gw1t + (size_t)t * NGH * DIN; K = DIN; N = NGH;
        k0 = tile * 64; n0 = 0;
    }
    int t = threadIdx.x;
#pragma unroll
    for (int i = 0; i < 16; ++i) {
        int idx = i * 256 + t;
        int kk = idx >> 6, nn = idx & 63;
        lds[kk * 65 + nn] = src[(size_t)(k0 + kk) * N + n0 + nn];
    }
    __syncthreads();
#pragma unroll
    for (int i = 0; i < 16; ++i) {
        int idx = i * 256 + t;
        int nn = idx >> 6, kk = idx & 63;
        dst[(size_t)(n0 + nn) * K + k0 + kk] = f2bf(lds[kk * 65 + nn]);
    }
}

// ---------------- fused expert (+gate) kernel ----------------
// blocks [0,2304): experts. 256 threads = 4 waves, wave tile 128x64.
//   BM=128, BN=256, BK=32, triple-buffered staging, prefetch depth 2,
//   ONE barrier per K-tile: vmcnt(6) -> barrier -> stage(kt+2) -> ds_read+MFMA(kt).
//   WAR safety: readers of buf[(kt-1)%3] consumed via MFMA (lgkm-enforced) before
//   the top-of-kt barrier; stage(kt+2) targets that same buffer after the barrier.
// blocks [2304,2560): gate path.
__global__ __launch_bounds__(256, 2) void k_expert_gate(
    const u16* __restrict__ xb, const u16* __restrict__ w1t, const u16* __restrict__ w2t,
    const float* __restrict__ sb1, const float* __restrict__ db1, const float* __restrict__ tb1,
    const float* __restrict__ sb2, const float* __restrict__ db2, const float* __restrict__ tb2,
    u16* __restrict__ eout,
    const u16* __restrict__ gw1t, const float* __restrict__ gb1,
    const float* __restrict__ gw2, const float* __restrict__ gb2, float* __restrict__ gates)
{
    // expert LDS: staging buf c @ c*24576: xs [0,8K), w1s [8K,24K)  (3 bufs, 72KB)
    //             GEMM2: hs [128][528B] @ 0 (67584 B, overlays staging)
    __shared__ __align__(128) char smem[73728];

    const int bid = blockIdx.x;
    const int tid = threadIdx.x;

    if (bid >= 2304) {
        // ================= GATE PATH =================
        u16* xs  = reinterpret_cast<u16*>(smem);
        u16* g1s = reinterpret_cast<u16*>(smem) + 4608;
        float* ghs = reinterpret_cast<float*>(smem);

        int m0 = (bid - 2304) * 64;
        int w = tid >> 6, lane = tid & 63;
        int wm = w & 1, wn = w >> 1;
        int l15 = lane & 15, lk = (lane >> 4) * 8, lr4 = (lane >> 4) * 4;

        f32x4 acc[2][6];
#pragma unroll
        for (int i = 0; i < 2; ++i)
#pragma unroll
            for (int j = 0; j < 6; ++j) acc[i][j] = (f32x4)0.f;

        const u16* xg = xb + (size_t)m0 * DIN;
        int srow = tid >> 3, su = (tid & 7) * 8;
        for (int kc = 0; kc < DIN / 64; ++kc) {
#pragma unroll
            for (int it = 0; it < 2; ++it) {
                int rr = srow + it * 32;
                *reinterpret_cast<uint4*>(&xs[rr * 72 + su]) =
                    *reinterpret_cast<const uint4*>(xg + (size_t)rr * DIN + kc * 64 + su);
            }
#pragma unroll
            for (int it = 0; it < 6; ++it) {
                int rr = srow + it * 32;
                *reinterpret_cast<uint4*>(&g1s[rr * 72 + su]) =
                    *reinterpret_cast<const uint4*>(gw1t + (size_t)rr * DIN + kc * 64 + su);
            }
            __syncthreads();
            s16x8 af[2][2], bfr[6][2];
#pragma unroll
            for (int mi = 0; mi < 2; ++mi)
#pragma unroll
                for (int kk = 0; kk < 2; ++kk)
                    af[mi][kk] = *reinterpret_cast<const s16x8*>(&xs[(wm * 32 + mi * 16 + l15) * 72 + kk * 32 + lk]);
#pragma unroll
            for (int nj = 0; nj < 6; ++nj)
#pragma unroll
                for (int kk = 0; kk < 2; ++kk)
                    bfr[nj][kk] = *reinterpret_cast<const s16x8*>(&g1s[(wn * 96 + nj * 16 + l15) * 72 + kk * 32 + lk]);
#pragma unroll
            for (int kk = 0; kk < 2; ++kk)
#pragma unroll
                for (int mi = 0; mi < 2; ++mi)
#pragma unroll
                    for (int nj = 0; nj < 6; ++nj)
                        acc[mi][nj] = __builtin_amdgcn_mfma_f32_16x16x32_bf16(af[mi][kk], bfr[nj][kk], acc[mi][nj], 0, 0, 0);
            __syncthreads();
        }
#pragma unroll
        for (int mi = 0; mi < 2; ++mi)
#pragma unroll
            for (int nj = 0; nj < 6; ++nj) {
                int col = wn * 96 + nj * 16 + l15;
                float bias = gb1[col];
#pragma unroll
                for (int r = 0; r < 4; ++r) {
                    int row = wm * 32 + mi * 16 + lr4 + r;
                    float v = acc[mi][nj][r] + bias;
                    ghs[row * 200 + col] = v > 0.f ? v : 0.f;
                }
            }
        __syncthreads();

        if (tid < 192) {
            int tt = tid >> 6, rr = tid & 63;
            float logit[NETOT];
#pragma unroll
            for (int e2 = 0; e2 < NETOT; ++e2) logit[e2] = gb2[tt * NETOT + e2];
            const float* g2 = gw2 + tt * NGH * NETOT;
            const float* gr = &ghs[rr * 200 + tt * 64];
            for (int g = 0; g < NGH; ++g) {
                float v = gr[g];
#pragma unroll
                for (int e2 = 0; e2 < NETOT; ++e2) logit[e2] += v * g2[g * NETOT + e2];
            }
            float m = logit[0];
#pragma unroll
            for (int e2 = 1; e2 < NETOT; ++e2) m = fmaxf(m, logit[e2]);
            float s = 0.f, p[NETOT];
#pragma unroll
            for (int e2 = 0; e2 < NETOT; ++e2) { p[e2] = __expf(logit[e2] - m); s += p[e2]; }
            float inv = 1.f / s;
            float* go = gates + (size_t)(m0 + rr) * (NT * NETOT) + tt * NETOT;
#pragma unroll
            for (int e2 = 0; e2 < NETOT; ++e2) go[e2] = p[e2] * inv;
        }
        return;
    }

    // ================= EXPERT PATH =================
    const int e  = bid >> 7;
    const int m0 = (bid & 127) * 128;
    const int w = tid >> 6, lane = tid & 63;     // 4 waves, wn = w
    const int l15 = lane & 15, q = lane >> 4;
    const int q16 = q * 16;
    const int swk = ((l15 >> 1) & 3) << 4;       // BK=32 row (64B) swizzle

    const u16* xg  = xb + (size_t)m0 * DIN;
    const u16* w1g = w1t + (size_t)e * H1 * DIN;
    const u16* w2g = w2t + (size_t)e * H2 * H1;
    const float* b1p = (e < 4) ? sb1 + e * H1 : (e < 12) ? db1 + (e - 4) * H1 : tb1 + (e - 12) * H1;
    const float* b2p = (e < 4) ? sb2 + e * H2 : (e < 12) ? db2 + (e - 4) * H2 : tb2 + (e - 12) * H2;

    // staging: per-lane inverse-swizzled global src, wave-uniform LDS dest
    const int sr = lane >> 2, sc = lane & 3;
    const u16* gx[2]; int lx[2];
#pragma unroll
    for (int j = 0; j < 2; ++j) {
        int row = w * 32 + j * 16 + sr;
        gx[j] = xg + (size_t)row * DIN + ((sc ^ ((row >> 1) & 3)) * 8);
        lx[j] = w * 2048 + j * 1024;           // + buf*24576
    }
    const u16* gw1[4]; int lw1[4];
#pragma unroll
    for (int j = 0; j < 4; ++j) {
        int row = w * 64 + j * 16 + sr;
        gw1[j] = w1g + (size_t)row * DIN + ((sc ^ ((row >> 1) & 3)) * 8);
        lw1[j] = 8192 + w * 4096 + j * 1024;   // + buf*24576
    }

    // fragment offsets within current buf
    int offX[8], offW[4];
#pragma unroll
    for (int mi = 0; mi < 8; ++mi)
        offX[mi] = (mi * 16 + l15) * 64 + (q16 ^ swk);
#pragma unroll
    for (int nj = 0; nj < 4; ++nj)
        offW[nj] = 8192 + (w * 64 + nj * 16 + l15) * 64 + (q16 ^ swk);

    f32x4 acc1[8][4];
#pragma unroll
    for (int i = 0; i < 8; ++i)
#pragma unroll
        for (int j = 0; j < 4; ++j) acc1[i][j] = (f32x4)0.f;

    // ---- GEMM1: h[128,256] = x[128,512] @ W1t^T, 16 K-tiles BK=32 ----
    // triple-buffered, depth 2, ONE barrier per kt.
    // prologue: kt=0 -> buf0, kt=1 -> buf1
#pragma unroll
    for (int j = 0; j < 2; ++j) GLDS16(gx[j], smem + lx[j]);
#pragma unroll
    for (int j = 0; j < 4; ++j) GLDS16(gw1[j], smem + lw1[j]);
#pragma unroll
    for (int j = 0; j < 2; ++j) GLDS16(gx[j] + 32, smem + 24576 + lx[j]);
#pragma unroll
    for (int j = 0; j < 4; ++j) GLDS16(gw1[j] + 32, smem + 24576 + lw1[j]);

    int cur = 0, stg = 2;   // buffer indices (x24576)
    for (int kt = 0; kt < 16; ++kt) {
        // wait for tile-kt's own 6 loads (oldest outstanding); newer stay in flight
        if (kt < 15) {
            asm volatile("s_waitcnt vmcnt(6)" ::: "memory");
        } else {
            asm volatile("s_waitcnt vmcnt(0)" ::: "memory");
        }
        __builtin_amdgcn_s_barrier();   // all waves: tile-kt staged AND tile-(kt-1) reads consumed

        if (kt < 14) {                  // stage kt+2 into buf[(kt-1)%3] -- WAR-safe past the barrier
            const int sb = stg * 24576, ko = (kt + 2) * 32;
#pragma unroll
            for (int j = 0; j < 2; ++j) GLDS16(gx[j] + ko, smem + sb + lx[j]);
#pragma unroll
            for (int j = 0; j < 4; ++j) GLDS16(gw1[j] + ko, smem + sb + lw1[j]);
        }

        const char* cb = smem + cur * 24576;
        s16x8 xf[8], wf[4];
#pragma unroll
        for (int nj = 0; nj < 4; ++nj) wf[nj] = *(const s16x8*)(cb + offW[nj]);
#pragma unroll
        for (int mi = 0; mi < 8; ++mi) xf[mi] = *(const s16x8*)(cb + offX[mi]);
        __builtin_amdgcn_s_setprio(1);
#pragma unroll
        for (int mi = 0; mi < 8; ++mi)
#pragma unroll
            for (int nj = 0; nj < 4; ++nj)   // SWAPPED: A=W1, B=x -> C col = m (l15), row = n (q*4+r)
                acc1[mi][nj] = __builtin_amdgcn_mfma_f32_16x16x32_bf16(wf[nj], xf[mi], acc1[mi][nj], 0, 0, 0);
        __builtin_amdgcn_s_setprio(0);

        cur = (cur == 2) ? 0 : cur + 1;
        stg = (stg == 2) ? 0 : stg + 1;
    }
    __syncthreads();   // last tile's reads consumed everywhere before hs overlay write

    // ---- h = relu(acc1 + b1) -> hs [128 rows][528 B] (padded rows) ----
#pragma unroll
    for (int mi = 0; mi < 8; ++mi) {
        const int m = mi * 16 + l15;
        char* rowp = smem + m * 528;
#pragma unroll
        for (int nj = 0; nj < 4; ++nj) {
            const int n0 = w * 64 + nj * 16 + q * 4;
            const float4 bv = *reinterpret_cast<const float4*>(b1p + n0);
            float v0 = fmaxf(acc1[mi][nj][0] + bv.x, 0.f);
            float v1 = fmaxf(acc1[mi][nj][1] + bv.y, 0.f);
            float v2 = fmaxf(acc1[mi][nj][2] + bv.z, 0.f);
            float v3 = fmaxf(acc1[mi][nj][3] + bv.w, 0.f);
            uint2 hv; hv.x = cvtpk(v0, v1); hv.y = cvtpk(v2, v3);
            *reinterpret_cast<uint2*>(rowp + n0 * 2) = hv;
        }
    }
    __syncthreads();

    // ---- GEMM2: o[128,128] = h[128,256] @ W2t^T; W2 from global; no barriers ----
    f32x4 acc2[8][2];
#pragma unroll
    for (int i = 0; i < 8; ++i)
#pragma unroll
        for (int j = 0; j < 2; ++j) acc2[i][j] = (f32x4)0.f;
    const u16* w2p0 = w2g + (size_t)(w * 32 + l15) * H1 + q * 8;
    const u16* w2p1 = w2g + (size_t)(w * 32 + 16 + l15) * H1 + q * 8;
#pragma unroll
    for (int kt2 = 0; kt2 < 8; ++kt2) {
        s16x8 wf2[2], hf[8];
        wf2[0] = *(const s16x8*)(w2p0 + kt2 * 32);
        wf2[1] = *(const s16x8*)(w2p1 + kt2 * 32);
#pragma unroll
        for (int mi = 0; mi < 8; ++mi)
            hf[mi] = *(const s16x8*)(smem + (mi * 16 + l15) * 528 + kt2 * 64 + q16);
#pragma unroll
        for (int mi = 0; mi < 8; ++mi)
#pragma unroll
            for (int pj = 0; pj < 2; ++pj)
                acc2[mi][pj] = __builtin_amdgcn_mfma_f32_16x16x32_bf16(hf[mi], wf2[pj], acc2[mi][pj], 0, 0, 0);
    }

    // ---- epilogue: relu(acc2 + b2) -> eout[e][b][h] bf16 ----
    u16* eo = eout + ((size_t)e * NB + m0) * H2;
#pragma unroll
    for (int mi = 0; mi < 8; ++mi)
#pragma unroll
        for (int pj = 0; pj < 2; ++pj) {
            const int p = w * 32 + pj * 16 + l15;
            const float bias = b2p[p];
#pragma unroll
            for (int r = 0; r < 4; ++r) {
                const int row = mi * 16 + q * 4 + r;
                float v = acc2[mi][pj][r] + bias;
                eo[(size_t)row * H2 + p] = f2bf(v > 0.f ? v : 0.f);
            }
        }
}

// ---------------- combine ----------------
__global__ __launch_bounds__(256) void k_combine(
    const u16* __restrict__ eout, const float* __restrict__ gates, float* __restrict__ out)
{
    int tid = threadIdx.x;
    int lr = tid >> 5, hq = tid & 31;
    int b = blockIdx.x * 8 + lr;
    int h0 = hq * 4;
    const float* g = gates + (size_t)b * (NT * NETOT);
    float o0[4] = {0, 0, 0, 0}, o1[4] = {0, 0, 0, 0}, o2[4] = {0, 0, 0, 0};
#pragma unroll
    for (int e = 0; e < NE; ++e) {
        ushort4 ev = *reinterpret_cast<const ushort4*>(&eout[((size_t)e * NB + b) * H2 + h0]);
        float v0 = bf2f(ev.x), v1 = bf2f(ev.y), v2 = bf2f(ev.z), v3 = bf2f(ev.w);
        if (e < 12) {
            float wa = g[e], wb = g[NETOT + e], wc = g[2 * NETOT + e];
            o0[0] += wa * v0; o0[1] += wa * v1; o0[2] += wa * v2; o0[3] += wa * v3;
            o1[0] += wb * v0; o1[1] += wb * v1; o1[2] += wb * v2; o1[3] += wb * v3;
            o2[0] += wc * v0; o2[1] += wc * v1; o2[2] += wc * v2; o2[3] += wc * v3;
        } else {
            int t = (e - 12) >> 1, te = (e - 12) & 1;
            float wt = g[t * NETOT + 12 + te];
            float* ot = (t == 0) ? o0 : (t == 1) ? o1 : o2;
            ot[0] += wt * v0; ot[1] += wt * v1; ot[2] += wt * v2; ot[3] += wt * v3;
        }
    }
    size_t base = (size_t)b * H2 + h0;
    *reinterpret_cast<float4*>(&out[0 * (size_t)NB * H2 + base]) = make_float4(o0[0], o0[1], o0[2], o0[3]);
    *reinterpret_cast<float4*>(&out[1 * (size_t)NB * H2 + base]) = make_float4(o1[0], o1[1], o1[2], o1[3]);
    *reinterpret_cast<float4*>(&out[2 * (size_t)NB * H2 + base]) = make_float4(o2[0], o2[1], o2[2], o2[3]);
}

extern "C" void kernel_launch(void* const* d_in, const int* in_sizes, int n_in,
                              void* d_out, int out_size, void* d_ws, size_t ws_size,
                              hipStream_t stream)
{
    const float* x   = (const float*)d_in[0];
    const float* sW1 = (const float*)d_in[2];
    const float* sb1 = (const float*)d_in[3];
    const float* sW2 = (const float*)d_in[4];
    const float* sb2 = (const float*)d_in[5];
    const float* dW1 = (const float*)d_in[6];
    const float* db1 = (const float*)d_in[7];
    const float* dW2 = (const float*)d_in[8];
    const float* db2 = (const float*)d_in[9];
    const float* tW1 = (const float*)d_in[10];
    const float* tb1 = (const float*)d_in[11];
    const float* tW2 = (const float*)d_in[12];
    const float* tb2 = (const float*)d_in[13];
    const float* gW1 = (const float*)d_in[14];
    const float* gb1 = (const float*)d_in[15];
    const float* gW2 = (const float*)d_in[16];
    const float* gb2 = (const float*)d_in[17];

    char* ws = (char*)d_ws;
    u16*  xb    = (u16*)(ws + 0);
    u16*  w1t   = (u16*)(ws + 16777216);
    u16*  w2t   = (u16*)(ws + 21495808);
    u16*  gw1t  = (u16*)(ws + 22675456);
    float* gates = (float*)(ws + 22872064);
    u16*  eout  = (u16*)(ws + 25624576);

    k_prep<<<dim3(8936), dim3(256), 0, stream>>>(x, xb, sW1, dW1, tW1, sW2, dW2, tW2, gW1, w1t, w2t, gw1t);
    k_expert_gate<<<dim3(2560), dim3(256), 0, stream>>>(xb, w1t, w2t, sb1, db1, tb1, sb2, db2, tb2,
                                                        eout, gw1t, gb1, gW2, gb2, gates);
    k_combine<<<dim3(NB / 8), dim3(256), 0, stream>>>(eout, gates, (float*)d_out);
}